// Round 2
// baseline (488.134 us; speedup 1.0000x reference)
//
#include <hip/hip_runtime.h>
#include <hip/hip_bf16.h>

#define N_NODES 4096
#define DIM 256
#define NHEAD 4
#define NEDGE 131072
#define MWORDS 128           // 4096 bits / 32 per mask row

#define BM 64
#define BN 64
#define BK 16

// ---------------------------------------------------------------- mask build
__global__ __launch_bounds__(256) void build_mask_kernel(const int* __restrict__ ei,
                                                         unsigned* __restrict__ mask) {
    const int t = blockIdx.x * blockDim.x + threadIdx.x;
    if (t < NEDGE) {
        const int r = ei[t] & (N_NODES - 1);
        const int c = ei[NEDGE + t] & (N_NODES - 1);
        atomicOr(&mask[r * MWORDS + (c >> 5)], 1u << (c & 31));
        atomicOr(&mask[c * MWORDS + (r >> 5)], 1u << (r & 31));
    } else if (t < NEDGE + N_NODES) {
        const int i = t - NEDGE;
        atomicOr(&mask[i * MWORDS + (i >> 5)], 1u << (i & 31));
    }
}

// ---------------------------------------------------------------- fp32 NT GEMM tile
// C[m][n] = sum_k A[m*lda+k] * B[n*ldb+k] + bias[n]
__device__ __forceinline__ void gemm_nt_64x64(const float* __restrict__ A, int lda,
                                              const float* __restrict__ B, int ldb,
                                              const float* __restrict__ bias,
                                              float* __restrict__ C, int ldc,
                                              int bm, int bn, int K) {
    __shared__ float As[BK][BM + 4];
    __shared__ float Bs[BK][BN + 4];
    const int tid = threadIdx.x;
    const int tx = tid & 15;
    const int ty = tid >> 4;
    const int lr = tid >> 2;         // 0..63 : row within tile for loads
    const int lc = (tid & 3) << 2;   // 0,4,8,12 : k-col within chunk
    float acc[4][4] = {{0.f, 0.f, 0.f, 0.f}, {0.f, 0.f, 0.f, 0.f},
                       {0.f, 0.f, 0.f, 0.f}, {0.f, 0.f, 0.f, 0.f}};
    const float* Aload = A + (bm + lr) * lda + lc;
    const float* Bload = B + (bn + lr) * ldb + lc;
    for (int k0 = 0; k0 < K; k0 += BK) {
        const float4 a4 = *(const float4*)(Aload + k0);
        const float4 b4 = *(const float4*)(Bload + k0);
        __syncthreads();
        As[lc + 0][lr] = a4.x; As[lc + 1][lr] = a4.y;
        As[lc + 2][lr] = a4.z; As[lc + 3][lr] = a4.w;
        Bs[lc + 0][lr] = b4.x; Bs[lc + 1][lr] = b4.y;
        Bs[lc + 2][lr] = b4.z; Bs[lc + 3][lr] = b4.w;
        __syncthreads();
#pragma unroll
        for (int k = 0; k < BK; ++k) {
            const float4 av = *(const float4*)&As[k][ty << 2];
            const float4 bv = *(const float4*)&Bs[k][tx << 2];
            acc[0][0] += av.x * bv.x; acc[0][1] += av.x * bv.y;
            acc[0][2] += av.x * bv.z; acc[0][3] += av.x * bv.w;
            acc[1][0] += av.y * bv.x; acc[1][1] += av.y * bv.y;
            acc[1][2] += av.y * bv.z; acc[1][3] += av.y * bv.w;
            acc[2][0] += av.z * bv.x; acc[2][1] += av.z * bv.y;
            acc[2][2] += av.z * bv.z; acc[2][3] += av.z * bv.w;
            acc[3][0] += av.w * bv.x; acc[3][1] += av.w * bv.y;
            acc[3][2] += av.w * bv.z; acc[3][3] += av.w * bv.w;
        }
    }
    const int col = bn + (tx << 2);
    const float4 bia = *(const float4*)&bias[col];
#pragma unroll
    for (int i = 0; i < 4; ++i) {
        const int row = bm + (ty << 2) + i;
        float4 r;
        r.x = acc[i][0] + bia.x;
        r.y = acc[i][1] + bia.y;
        r.z = acc[i][2] + bia.z;
        r.w = acc[i][3] + bia.w;
        *(float4*)&C[row * ldc + col] = r;
    }
}

// q/k/v projections: z = op*4 + head ; out[h][n][e] = x @ W[h]^T + b[h]
__global__ __launch_bounds__(256) void qkv_kernel(const float* __restrict__ x,
                                                  const float* __restrict__ Wq, const float* __restrict__ bq,
                                                  const float* __restrict__ Wk, const float* __restrict__ bk,
                                                  const float* __restrict__ Wv, const float* __restrict__ bv,
                                                  float* __restrict__ q, float* __restrict__ k,
                                                  float* __restrict__ v) {
    const int z = blockIdx.z;
    const int op = z >> 2;
    const int h = z & 3;
    const float* W;
    const float* b;
    float* out;
    if (op == 0)      { W = Wq; b = bq; out = q; }
    else if (op == 1) { W = Wk; b = bk; out = k; }
    else              { W = Wv; b = bv; out = v; }
    gemm_nt_64x64(x, DIM, W + h * DIM * DIM, DIM, b + h * DIM,
                  out + h * N_NODES * DIM, DIM,
                  blockIdx.x * BM, blockIdx.y * BN, DIM);
}

// per-head out-proj, written straight into concat layout [N, H*D]
__global__ __launch_bounds__(256) void headout_kernel(const float* __restrict__ o,
                                                      const float* __restrict__ Wo,
                                                      const float* __restrict__ bo,
                                                      float* __restrict__ concat) {
    const int h = blockIdx.z;
    gemm_nt_64x64(o + h * N_NODES * DIM, DIM, Wo + h * DIM * DIM, DIM, bo + h * DIM,
                  concat + h * DIM, NHEAD * DIM,
                  blockIdx.x * BM, blockIdx.y * BN, DIM);
}

// out = concat [N,1024] @ Wp^T + bp -> [N,256]
__global__ __launch_bounds__(256) void finalproj_kernel(const float* __restrict__ concat,
                                                        const float* __restrict__ Wp,
                                                        const float* __restrict__ bp,
                                                        float* __restrict__ outp) {
    gemm_nt_64x64(concat, NHEAD * DIM, Wp, NHEAD * DIM, bp,
                  outp, DIM,
                  blockIdx.x * BM, blockIdx.y * BN, NHEAD * DIM);
}

// ---------------------------------------------------------------- sparse attention
// one block per node; wave w handles head w; lanes hold 4 contiguous dims
__global__ __launch_bounds__(256) void attn_sparse_kernel(const unsigned* __restrict__ mask,
                                                          const float* __restrict__ q,
                                                          const float* __restrict__ k,
                                                          const float* __restrict__ v,
                                                          float* __restrict__ o) {
    __shared__ unsigned mrow[MWORDS];
    const int i = blockIdx.x;
    const int tid = threadIdx.x;
    if (tid < MWORDS) mrow[tid] = mask[i * MWORDS + tid];
    __syncthreads();
    const int lane = tid & 63;
    const int h = tid >> 6;
    const float4 qv = *(const float4*)&q[(h * N_NODES + i) * DIM + (lane << 2)];
    float4 oa = {0.f, 0.f, 0.f, 0.f};
    float denom = 0.f;
    for (int w = 0; w < MWORDS; ++w) {
        unsigned m = mrow[w];
        while (m) {
            const int b = __ffs(m) - 1;
            m &= m - 1;
            const int j = (w << 5) + b;
            const float4 kv = *(const float4*)&k[(h * N_NODES + j) * DIM + (lane << 2)];
            float p = qv.x * kv.x + qv.y * kv.y + qv.z * kv.z + qv.w * kv.w;
            p += __shfl_xor(p, 32);
            p += __shfl_xor(p, 16);
            p += __shfl_xor(p, 8);
            p += __shfl_xor(p, 4);
            p += __shfl_xor(p, 2);
            p += __shfl_xor(p, 1);
            const float wt = expf(p * 0.0625f);   // 1/sqrt(256)
            denom += wt;
            const float4 vv = *(const float4*)&v[(h * N_NODES + j) * DIM + (lane << 2)];
            oa.x += wt * vv.x; oa.y += wt * vv.y;
            oa.z += wt * vv.z; oa.w += wt * vv.w;
        }
    }
    const float inv = 1.0f / denom;
    float4 r;
    r.x = oa.x * inv; r.y = oa.y * inv; r.z = oa.z * inv; r.w = oa.w * inv;
    *(float4*)&o[(h * N_NODES + i) * DIM + (lane << 2)] = r;
}

// ---------------------------------------------------------------- layernorm
__global__ __launch_bounds__(256) void layernorm_kernel(const float* __restrict__ inp,
                                                        const float* __restrict__ gamma,
                                                        const float* __restrict__ beta,
                                                        float* __restrict__ out) {
    const int row = (blockIdx.x << 2) + (threadIdx.x >> 6);
    const int lane = threadIdx.x & 63;
    const float4 xv = *(const float4*)&inp[row * DIM + (lane << 2)];
    float s = xv.x + xv.y + xv.z + xv.w;
#pragma unroll
    for (int off = 32; off; off >>= 1) s += __shfl_xor(s, off);
    const float mu = s * (1.0f / DIM);
    const float dx = xv.x - mu, dy = xv.y - mu, dz = xv.z - mu, dw = xv.w - mu;
    float sq = dx * dx + dy * dy + dz * dz + dw * dw;
#pragma unroll
    for (int off = 32; off; off >>= 1) sq += __shfl_xor(sq, off);
    const float inv = 1.0f / sqrtf(sq * (1.0f / DIM) + 1e-5f);
    const float4 gv = *(const float4*)&gamma[lane << 2];
    const float4 bv = *(const float4*)&beta[lane << 2];
    float4 r;
    r.x = dx * inv * gv.x + bv.x;
    r.y = dy * inv * gv.y + bv.y;
    r.z = dz * inv * gv.z + bv.z;
    r.w = dw * inv * gv.w + bv.w;
    *(float4*)&out[row * DIM + (lane << 2)] = r;
}

// ---------------------------------------------------------------- launcher
extern "C" void kernel_launch(void* const* d_in, const int* in_sizes, int n_in,
                              void* d_out, int out_size, void* d_ws, size_t ws_size,
                              hipStream_t stream) {
    const float* x     = (const float*)d_in[0];
    const int*   ei    = (const int*)d_in[1];
    const float* Wq    = (const float*)d_in[2];
    const float* bq    = (const float*)d_in[3];
    const float* Wk    = (const float*)d_in[4];
    const float* bk    = (const float*)d_in[5];
    const float* Wv    = (const float*)d_in[6];
    const float* bv    = (const float*)d_in[7];
    const float* Wo    = (const float*)d_in[8];
    const float* bo    = (const float*)d_in[9];
    const float* Wp    = (const float*)d_in[10];
    const float* bp    = (const float*)d_in[11];
    const float* gamma = (const float*)d_in[12];
    const float* beta  = (const float*)d_in[13];
    float* outf = (float*)d_out;

    char* ws = (char*)d_ws;
    unsigned* mask = (unsigned*)ws;                       // 2 MB
    float* q = (float*)(ws + (size_t)(2 << 20));          // 16 MB each
    float* k = q + (size_t)NHEAD * N_NODES * DIM;
    float* v = k + (size_t)NHEAD * N_NODES * DIM;
    float* o = v + (size_t)NHEAD * N_NODES * DIM;
    float* concat = q;                                    // alias (q dead after attn)
    float* outp   = k;                                    // alias (k dead after attn)

    hipMemsetAsync(mask, 0, N_NODES * MWORDS * sizeof(unsigned), stream);
    build_mask_kernel<<<(NEDGE + N_NODES + 255) / 256, 256, 0, stream>>>(ei, mask);

    qkv_kernel<<<dim3(N_NODES / BM, DIM / BN, 12), 256, 0, stream>>>(
        x, Wq, bq, Wk, bk, Wv, bv, q, k, v);

    attn_sparse_kernel<<<N_NODES, 256, 0, stream>>>(mask, q, k, v, o);

    headout_kernel<<<dim3(N_NODES / BM, DIM / BN, NHEAD), 256, 0, stream>>>(o, Wo, bo, concat);

    finalproj_kernel<<<dim3(N_NODES / BM, DIM / BN), 256, 0, stream>>>(concat, Wp, bp, outp);

    layernorm_kernel<<<N_NODES / 4, 256, 0, stream>>>(outp, gamma, beta, outf);
}